// Round 6
// baseline (350.755 us; speedup 1.0000x reference)
//
#include <hip/hip_runtime.h>
#include <cstdint>

#define B_ 128
#define N_ 1024
#define D_ 16
#define U_ 128
#define M_ (B_*N_)     // 131072 rows (b,n)
#define K_ 144         // D_+U_
#define KP 192         // padded K for MFMA (6 x 32)
#define CAP 48         // ELL row capacity (~11 nnz expected; zero-filled to 48)
#define SSTR 10        // LDS row stride in floats (40B): banks (10J+2q)%32

typedef unsigned short u16;
typedef unsigned int   u32;
typedef __attribute__((ext_vector_type(8))) short bf16x8;
typedef __attribute__((ext_vector_type(4))) float f32x4;

__device__ __forceinline__ float bf2f(u16 h){ return __uint_as_float(((u32)h) << 16); }
__device__ __forceinline__ u16 f2bf(float f){
    u32 u = __float_as_uint(f);
    return (u16)((u + 0x7FFFu + ((u >> 16) & 1u)) >> 16);
}
__device__ __forceinline__ float sig_(float x){ return 1.0f / (1.0f + __expf(-x)); }

// ---------------- K0: compact dense support -> ELL; zero-fill to CAP --------
__global__ void k_ell(const float* __restrict__ sup, float* __restrict__ vals,
                      int* __restrict__ cols, int* __restrict__ nnz)
{
    int wid  = (blockIdx.x * blockDim.x + threadIdx.x) >> 6;  // row of support
    int lane = threadIdx.x & 63;
    if (wid >= N_) return;
    const float* row = sup + (size_t)wid * N_;
    int base = 0;
    for (int step = 0; step < N_/64; ++step){
        int j = step*64 + lane;
        float v = row[j];
        unsigned long long m = __ballot(v != 0.0f);
        int pos = base + __popcll(m & ((1ull << lane) - 1ull));
        if (v != 0.0f && pos < CAP){ vals[wid*CAP + pos] = v; cols[wid*CAP + pos] = j; }
        base += __popcll(m);
    }
    int cnt = base < CAP ? base : CAP;
    for (int p = cnt + lane; p < CAP; p += 64){
        vals[wid*CAP + p] = 0.0f;
        cols[wid*CAP + p] = 0;
    }
    if (lane == 0) nnz[wid] = (cnt + 3) & ~3;   // padded count for tail loop
}

// ---------------- K0b: transpose weights to bf16 [col][KP] ------------------
__global__ void k_prep(const float* __restrict__ kr, const float* __restrict__ kc,
                       u16* __restrict__ wr_t, u16* __restrict__ wc_t)
{
    int t = blockIdx.x * 256 + threadIdx.x;      // grid covers 256*KP + 128*KP
    if (t < 256*KP){
        int col = t / KP, k = t % KP;
        wr_t[t] = f2bf(k < K_ ? kr[k*256 + col] : 0.0f);
    } else {
        int q = t - 256*KP;
        int col = q / KP, k = q % KP;
        wc_t[q] = f2bf(k < K_ ? kc[k*128 + col] : 0.0f);
    }
}

// =============== LDS-staged SpMM (1 lane per node, 8 cols per chunk) ========
// s_hx: 1024 rows x 8 f32 cols at stride SSTR=10 floats. b64 read of row J,
// pair q -> banks (10J+2q)%32: 16 bases, ~4 req/bank = structural b64 minimum.
// ELL per node loaded by its own lane only (no x4 duplication).

#define GQ8(JJ, WW)                                                            \
    {   const float* hr = &s_hx[(int)(JJ)*SSTR];                               \
        float2 h0 = *(const float2*)(hr);   float2 h1 = *(const float2*)(hr+2);\
        float2 h2 = *(const float2*)(hr+4); float2 h3 = *(const float2*)(hr+6);\
        a0 = fmaf((WW),h0.x,a0); a1 = fmaf((WW),h0.y,a1);                      \
        a2 = fmaf((WW),h1.x,a2); a3 = fmaf((WW),h1.y,a3);                      \
        a4 = fmaf((WW),h2.x,a4); a5 = fmaf((WW),h2.y,a5);                      \
        a6 = fmaf((WW),h3.x,a6); a7 = fmaf((WW),h3.y,a7); }

#define GB4(T0)                                                                \
    {   float4 wv = *(const float4*)(vt + (T0));                               \
        int4   jv = *(const int4*)(ct + (T0));                                 \
        GQ8(jv.x, wv.x); GQ8(jv.y, wv.y); GQ8(jv.z, wv.z); GQ8(jv.w, wv.w); }

#define PACK_STORE(DSTPTR)                                                     \
    {   uint4 pk;                                                              \
        pk.x = (u32)f2bf(a0) | ((u32)f2bf(a1) << 16);                          \
        pk.y = (u32)f2bf(a2) | ((u32)f2bf(a3) << 16);                          \
        pk.z = (u32)f2bf(a4) | ((u32)f2bf(a5) << 16);                          \
        pk.w = (u32)f2bf(a6) | ((u32)f2bf(a7) << 16);                          \
        *(uint4*)(DSTPTR) = pk; }

// ---------------- K1: agg[:,0:144] = support @ [y_basis | hx]  (bf16 out) ---
// chunks 0..17 compute 8 cols each; chunks 18..23 zero-fill pad cols 144..191.
__global__ __launch_bounds__(256, 4) void k_spmm1(
        const float* __restrict__ x, const float* __restrict__ hx,
        const float* __restrict__ vals, const int* __restrict__ cols,
        const int* __restrict__ nnz, u16* __restrict__ agg)
{
    __shared__ float s_hx[1024*SSTR];      // 40 KB
    const int chunk = blockIdx.x;          // 0..23
    const int b     = blockIdx.y;
    const int tid   = threadIdx.x;

    if (chunk >= 18){                      // zero-fill pad columns 144..191
        int cb = 144 + (chunk - 18) * 8;
        uint4 z = {0,0,0,0};
        for (int node = tid; node < 1024; node += 256){
            size_t m = (size_t)(b<<10) + node;
            *(uint4*)&agg[m*KP + cb] = z;
        }
        return;
    }

    const int cb = chunk * 8;              // xs col base (0..143)
    for (int q = tid; q < 2048; q += 256){
        int row = q >> 1, half = q & 1;
        int xscol = cb + half*4;
        float4 v;
        if (chunk < 2)
            v = *(const float4*)&x[((size_t)((b<<10)+row))*16 + xscol];
        else
            v = *(const float4*)&hx[((size_t)((b<<10)+row))*128 + (xscol-16)];
        float* dst = &s_hx[row*SSTR + half*4];
        *(float2*)dst     = make_float2(v.x, v.y);
        *(float2*)(dst+2) = make_float2(v.z, v.w);
    }
    __syncthreads();

    for (int node = tid; node < 1024; node += 256){
        int c = nnz[node];
        const float* vt = vals + node*CAP;
        const int*   ct = cols + node*CAP;
        float a0=0.f,a1=0.f,a2=0.f,a3=0.f,a4=0.f,a5=0.f,a6=0.f,a7=0.f;
        GB4(0) GB4(4) GB4(8) GB4(12)                  // branch-free (zero-padded)
        for (int t0 = 16; t0 < c; t0 += 4) GB4(t0)    // rare tail
        size_t m = (size_t)(b<<10) + node;
        PACK_STORE(&agg[m*KP + cb])
    }
}

// ---------------- K3: agg[:,16:144] = support @ (r * hx)  (bf16 out) --------
__global__ __launch_bounds__(256, 4) void k_spmm2(
        const u16* __restrict__ value, const float* __restrict__ hx,
        const float* __restrict__ vals, const int* __restrict__ cols,
        const int* __restrict__ nnz, u16* __restrict__ agg)
{
    __shared__ float s_hx[1024*SSTR];      // 40 KB
    const int chunk = blockIdx.x;          // 0..15 over hx cols
    const int b     = blockIdx.y;
    const int tid   = threadIdx.x;
    const int cb    = chunk * 8;

    for (int q = tid; q < 2048; q += 256){
        int row = q >> 1, half = q & 1;
        int hxcol = cb + half*4;
        size_t nb = (size_t)((b<<10)+row);
        float4 h = *(const float4*)&hx[nb*128 + hxcol];
        ushort4 rv = *(const ushort4*)&value[nb*256 + hxcol];  // r = cols 0..127
        float* dst = &s_hx[row*SSTR + half*4];
        *(float2*)dst     = make_float2(bf2f(rv.x)*h.x, bf2f(rv.y)*h.y);
        *(float2*)(dst+2) = make_float2(bf2f(rv.z)*h.z, bf2f(rv.w)*h.w);
    }
    __syncthreads();

    for (int node = tid; node < 1024; node += 256){
        int c = nnz[node];
        const float* vt = vals + node*CAP;
        const int*   ct = cols + node*CAP;
        float a0=0.f,a1=0.f,a2=0.f,a3=0.f,a4=0.f,a5=0.f,a6=0.f,a7=0.f;
        GB4(0) GB4(4) GB4(8) GB4(12)
        for (int t0 = 16; t0 < c; t0 += 4) GB4(t0)
        size_t m = (size_t)(b<<10) + node;
        PACK_STORE(&agg[m*KP + D_ + cb])
    }
}

// ============== MFMA GEMM core (bf16 inputs, f32 accum) ====================
// 128x128 tile, 4 waves (2x2), each wave 4x4 fragments of 16x16x32.
// LDS: A[128][72] + W[128][72] bf16 (stride 72 -> 2-way/free bank pattern).
// A-frag lane map: row=l&15, k=(l>>4)*8+j ; C/D: col=l&15, row=(l>>4)*4+reg.

#define GEMM_STAGE(DST, SRC, BASE)                                             \
    _Pragma("unroll")                                                          \
    for (int i = 0; i < 4; ++i){                                               \
        int q = tid + i*256;                                                   \
        int r_ = q >> 3, sl = q & 7;                                           \
        uint4 v = *(const uint4*)((SRC) + (size_t)((BASE)+r_)*KP + kb + sl*8); \
        *(uint4*)((DST) + r_*72 + sl*8) = v;                                   \
    }

#define GEMM_CORE                                                              \
    for (int kb = 0; kb < KP; kb += 64){                                       \
        __syncthreads();                                                       \
        GEMM_STAGE(a_s, agg, rb)                                               \
        GEMM_STAGE(w_s, wt, cb)                                                \
        __syncthreads();                                                       \
        _Pragma("unroll")                                                      \
        for (int ks = 0; ks < 2; ++ks){                                        \
            bf16x8 af[4], bfv[4];                                              \
            _Pragma("unroll")                                                  \
            for (int f = 0; f < 4; ++f){                                       \
                af[f]  = *(const bf16x8*)(a_s + (wr + f*16 + lrow)*72 + ks*32 + lk); \
                bfv[f] = *(const bf16x8*)(w_s + (wc + f*16 + lrow)*72 + ks*32 + lk); \
            }                                                                  \
            _Pragma("unroll")                                                  \
            for (int fr = 0; fr < 4; ++fr)                                     \
                _Pragma("unroll")                                              \
                for (int fc = 0; fc < 4; ++fc)                                 \
                    acc[fr][fc] = __builtin_amdgcn_mfma_f32_16x16x32_bf16(     \
                        af[fr], bfv[fc], acc[fr][fc], 0, 0, 0);                \
        }                                                                      \
    }

// ---------------- K2: value = sigmoid(agg @ kernel_r) -> bf16 ---------------
__global__ __launch_bounds__(256) void k_gemm1(const u16* __restrict__ agg,
        const u16* __restrict__ wt, u16* __restrict__ value)
{
    __shared__ u16 a_s[128*72];
    __shared__ u16 w_s[128*72];
    const int rb = blockIdx.x * 128, cb = blockIdx.y * 128;
    const int tid = threadIdx.x;
    const int wid = tid >> 6, lane = tid & 63;
    const int wr = (wid >> 1) * 64, wc = (wid & 1) * 64;
    const int lrow = lane & 15, lk = (lane >> 4) * 8;
    f32x4 acc[4][4] = {};
    GEMM_CORE
    const int rg = (lane >> 4) * 4;
    #pragma unroll
    for (int fr = 0; fr < 4; ++fr)
        #pragma unroll
        for (int fc = 0; fc < 4; ++fc)
            #pragma unroll
            for (int j = 0; j < 4; ++j){
                int row = rb + wr + fr*16 + rg + j;
                int col = cb + wc + fc*16 + lrow;
                value[(size_t)row*256 + col] = f2bf(sig_(acc[fr][fc][j]));
            }
}

// ---------------- K4: c=tanh(agg@kernel_c); new_state = hx*u + c*(1-u) -----
// value (bf16 r|u) lives IN the ns output slot; block owns rows rb..rb+127
// entirely (grid 1024x1): read u -> barrier -> store ns.
__global__ __launch_bounds__(256) void k_gemm2(const u16* __restrict__ agg,
        const u16* __restrict__ wt, const float* __restrict__ hx,
        const u16* value, float* ns_out)
{
    __shared__ u16 a_s[128*72];
    __shared__ u16 w_s[128*72];
    const int rb = blockIdx.x * 128, cb = 0;
    const int tid = threadIdx.x;
    const int wid = tid >> 6, lane = tid & 63;
    const int wr = (wid >> 1) * 64, wc = (wid & 1) * 64;
    const int lrow = lane & 15, lk = (lane >> 4) * 8;
    f32x4 acc[4][4] = {};
    GEMM_CORE
    const int rg = (lane >> 4) * 4;
    float ov[4][4][4];
    #pragma unroll
    for (int fr = 0; fr < 4; ++fr)
        #pragma unroll
        for (int fc = 0; fc < 4; ++fc)
            #pragma unroll
            for (int j = 0; j < 4; ++j){
                int row = rb + wr + fr*16 + rg + j;
                int col = wc + fc*16 + lrow;
                float u = bf2f(value[(size_t)row*256 + 128 + col]);
                float h = hx[(size_t)row*128 + col];
                float c = tanhf(acc[fr][fc][j]);
                ov[fr][fc][j] = h*u + c*(1.0f - u);
            }
    __syncthreads();   // all u-loads complete before anyone overwrites the slot
    #pragma unroll
    for (int fr = 0; fr < 4; ++fr)
        #pragma unroll
        for (int fc = 0; fc < 4; ++fc)
            #pragma unroll
            for (int j = 0; j < 4; ++j){
                int row = rb + wr + fr*16 + rg + j;
                int col = wc + fc*16 + lrow;
                ns_out[(size_t)row*128 + col] = ov[fr][fc][j];
            }
}

// ------- K5: o = [new_state | y_basis] @ w_out + b_out + new_delta; + nd ----
__global__ __launch_bounds__(256) void k_out(const float* __restrict__ ns,
        const float* __restrict__ x, const float* __restrict__ delta,
        const float* __restrict__ wo, const float* __restrict__ bo,
        const float* __restrict__ wb, const float* __restrict__ bb,
        const float* __restrict__ lam,
        float* __restrict__ o, float* __restrict__ nd_out)
{
    __shared__ float ns_s[64][132];
    __shared__ float yb_s[64][20];
    __shared__ float yr_s[64][20];
    __shared__ float w_s[144][16];
    __shared__ float wb_s[16][16];
    __shared__ float bo_s[16], bb_s[16];
    int rowbase = blockIdx.x * 64;
    int tid = threadIdx.x;
    const float* yr = x + (size_t)M_ * D_;      // x[1] = y_res
    #pragma unroll
    for (int jj = 0; jj < 8; ++jj){
        int q = tid + 256*jj;           // 2048 float4 = 64 rows x 128
        int row = q >> 5, c4 = (q & 31) * 4;
        *(float4*)&ns_s[row][c4] = *(const float4*)&ns[(size_t)(rowbase + row)*U_ + c4];
    }
    {
        int row = tid >> 2, c4 = (tid & 3) * 4;   // 256 float4 = 64 rows x 16
        *(float4*)&yb_s[row][c4] = *(const float4*)&x[(size_t)(rowbase + row)*D_ + c4];
        *(float4*)&yr_s[row][c4] = *(const float4*)&yr[(size_t)(rowbase + row)*D_ + c4];
    }
    #pragma unroll
    for (int jj = 0; jj < 3; ++jj){
        int q = tid + 256*jj;
        if (q < 576){ int k = q >> 2, d4 = (q & 3) * 4;
            *(float4*)&w_s[k][d4] = *(const float4*)&wo[k*D_ + d4]; }
    }
    wb_s[tid >> 4][tid & 15] = wb[tid];          // 256 = 16x16
    if (tid < 16){ bo_s[tid] = bo[tid]; bb_s[tid] = bb[tid]; }
    __syncthreads();
    int row = tid >> 2, d0 = (tid & 3) * 4;
    float4 acc = make_float4(0.f,0.f,0.f,0.f);
    for (int k = 0; k < U_; ++k){
        float cs = ns_s[row][k];
        float4 w = *(const float4*)&w_s[k][d0];
        acc.x = fmaf(cs, w.x, acc.x); acc.y = fmaf(cs, w.y, acc.y);
        acc.z = fmaf(cs, w.z, acc.z); acc.w = fmaf(cs, w.w, acc.w);
    }
    #pragma unroll
    for (int k = 0; k < D_; ++k){
        float cs = yb_s[row][k];
        float4 w = *(const float4*)&w_s[U_ + k][d0];
        acc.x = fmaf(cs, w.x, acc.x); acc.y = fmaf(cs, w.y, acc.y);
        acc.z = fmaf(cs, w.z, acc.z); acc.w = fmaf(cs, w.w, acc.w);
    }
    float4 dacc = make_float4(bb_s[d0], bb_s[d0+1], bb_s[d0+2], bb_s[d0+3]);
    #pragma unroll
    for (int k = 0; k < D_; ++k){
        float yv = yr_s[row][k];
        float4 w = *(const float4*)&wb_s[k][d0];
        dacc.x = fmaf(yv, w.x, dacc.x); dacc.y = fmaf(yv, w.y, dacc.y);
        dacc.z = fmaf(yv, w.z, dacc.z); dacc.w = fmaf(yv, w.w, dacc.w);
    }
    size_t off = (size_t)(rowbase + row)*D_ + d0;
    float4 dl = *(const float4*)&delta[off];
    float lm = lam[0];
    float nd4[4];
    float yv4[4] = {yr_s[row][d0], yr_s[row][d0+1], yr_s[row][d0+2], yr_s[row][d0+3]};
    float dv4[4] = {fmaxf(dacc.x,0.f), fmaxf(dacc.y,0.f), fmaxf(dacc.z,0.f), fmaxf(dacc.w,0.f)};
    float dl4[4] = {dl.x, dl.y, dl.z, dl.w};
    #pragma unroll
    for (int j = 0; j < 4; ++j){
        float pt = sig_(yv4[j] + 0.5f * sqrtf(fabsf(dl4[j] + 1e-9f)));
        nd4[j] = lm * (2.0f * pt - 1.0f) * dv4[j];
    }
    float4 bov = *(const float4*)&bo_s[d0];
    float4 ov = make_float4(acc.x + bov.x + nd4[0], acc.y + bov.y + nd4[1],
                            acc.z + bov.z + nd4[2], acc.w + bov.w + nd4[3]);
    *(float4*)&nd_out[off] = make_float4(nd4[0], nd4[1], nd4[2], nd4[3]);
    *(float4*)&o[off] = ov;
}

extern "C" void kernel_launch(void* const* d_in, const int* in_sizes, int n_in,
                              void* d_out, int out_size, void* d_ws, size_t ws_size,
                              hipStream_t stream)
{
    const float* x        = (const float*)d_in[0];
    const float* hx       = (const float*)d_in[1];
    const float* delta    = (const float*)d_in[2];
    const float* support  = (const float*)d_in[3];
    const float* kernel_r = (const float*)d_in[4];
    const float* kernel_c = (const float*)d_in[5];
    const float* w_out    = (const float*)d_in[6];
    const float* b_out    = (const float*)d_in[7];
    const float* w_basis  = (const float*)d_in[8];
    const float* b_basis  = (const float*)d_in[9];
    const float* lam      = (const float*)d_in[10];

    float* out = (float*)d_out;
    float* o   = out;                    // (B,N,D)   2,097,152
    float* ns  = out + 2097152;          // (B,N*U)  16,777,216
    float* nd  = out + 18874368;         // (B,N,D)   2,097,152
    u16*   value = (u16*)ns;             // bf16 [M][256] lives in ns slot

    char* ws = (char*)d_ws;
    float* ell_vals = (float*)ws;                       // 1024*48*4
    int*   ell_cols = (int*)(ws + 1024*CAP*4);          // 1024*48*4
    int*   ell_nnz  = (int*)(ws + 2*1024*CAP*4);        // 1024*4
    u16*   agg      = (u16*)(ws + (1 << 20));           // [M][192] bf16 = 50.3 MB
    u16*   wr_t     = (u16*)(ws + (1 << 20) + (size_t)M_*KP*2);          // 256*192
    u16*   wc_t     = wr_t + 256*KP;                                     // 128*192

    k_ell  <<<256, 256, 0, stream>>>(support, ell_vals, ell_cols, ell_nnz);
    k_prep <<<(256*KP + 128*KP)/256, 256, 0, stream>>>(kernel_r, kernel_c, wr_t, wc_t);
    k_spmm1<<<dim3(24,128), 256, 0, stream>>>(x, hx, ell_vals, ell_cols, ell_nnz, agg);
    k_gemm1<<<dim3(M_/128, 2), 256, 0, stream>>>(agg, wr_t, value);
    k_spmm2<<<dim3(16,128), 256, 0, stream>>>(value, hx, ell_vals, ell_cols, ell_nnz, agg);
    k_gemm2<<<M_/128, 256, 0, stream>>>(agg, wc_t, hx, value, ns);
    k_out  <<<M_/64, 256, 0, stream>>>(ns, x, delta, w_out, b_out,
                                       w_basis, b_basis, lam, o, nd);
}

// Round 7
// 237.423 us; speedup vs baseline: 1.4773x; 1.4773x over previous
//
#include <hip/hip_runtime.h>
#include <cstdint>

#define B_ 128
#define N_ 1024
#define D_ 16
#define U_ 128
#define M_ (B_*N_)     // 131072 rows (b,n)
#define K_ 144         // D_+U_
#define KP 192         // padded K for MFMA (6 x 32)
#define CAP 48         // ELL row capacity (~11 nnz expected; zero-filled to 48)

typedef unsigned short u16;
typedef unsigned int   u32;
typedef __attribute__((ext_vector_type(8))) short bf16x8;
typedef __attribute__((ext_vector_type(4))) float f32x4;

__device__ __forceinline__ float bf2f(u16 h){ return __uint_as_float(((u32)h) << 16); }
__device__ __forceinline__ u16 f2bf(float f){
    u32 u = __float_as_uint(f);
    return (u16)((u + 0x7FFFu + ((u >> 16) & 1u)) >> 16);
}
__device__ __forceinline__ float sig_(float x){ return 1.0f / (1.0f + __expf(-x)); }

// ---------------- K0: compact dense support -> ELL; zero-fill to CAP --------
__global__ void k_ell(const float* __restrict__ sup, float* __restrict__ vals,
                      int* __restrict__ cols, int* __restrict__ nnz)
{
    int wid  = (blockIdx.x * blockDim.x + threadIdx.x) >> 6;  // row of support
    int lane = threadIdx.x & 63;
    if (wid >= N_) return;
    const float* row = sup + (size_t)wid * N_;
    int base = 0;
    for (int step = 0; step < N_/64; ++step){
        int j = step*64 + lane;
        float v = row[j];
        unsigned long long m = __ballot(v != 0.0f);
        int pos = base + __popcll(m & ((1ull << lane) - 1ull));
        if (v != 0.0f && pos < CAP){ vals[wid*CAP + pos] = v; cols[wid*CAP + pos] = j; }
        base += __popcll(m);
    }
    int cnt = base < CAP ? base : CAP;
    for (int p = cnt + lane; p < CAP; p += 64){
        vals[wid*CAP + p] = 0.0f;
        cols[wid*CAP + p] = 0;
    }
    if (lane == 0) nnz[wid] = (cnt + 3) & ~3;   // padded count for tail loop
}

// ---------------- K0b: transpose weights to bf16 [col][KP] ------------------
__global__ void k_prep(const float* __restrict__ kr, const float* __restrict__ kc,
                       u16* __restrict__ wr_t, u16* __restrict__ wc_t)
{
    int t = blockIdx.x * 256 + threadIdx.x;      // grid covers 256*KP + 128*KP
    if (t < 256*KP){
        int col = t / KP, k = t % KP;
        wr_t[t] = f2bf(k < K_ ? kr[k*256 + col] : 0.0f);
    } else {
        int q = t - 256*KP;
        int col = q / KP, k = q % KP;
        wc_t[q] = f2bf(k < K_ ? kc[k*128 + col] : 0.0f);
    }
}

// =============== LDS-staged SpMM (round-5 layout, 512 threads) ==============
// One block per (batch b, 16-col chunk). xs chunk staged in LDS, XOR-swizzled
// float4 slots: slot = row*4 + (quad ^ (row&3)). 4 lanes per node (16 nodes x
// 4 quads per wave) -> proven near-minimal bank pattern. ELL from global (L2).

#define GQ(JJ, WW)                                                             \
    {   float4 h = s4[(int)(JJ)*4 + (cq ^ ((int)(JJ) & 3))];                   \
        acc.x = fmaf((WW), h.x, acc.x); acc.y = fmaf((WW), h.y, acc.y);        \
        acc.z = fmaf((WW), h.z, acc.z); acc.w = fmaf((WW), h.w, acc.w); }

#define GB(T0)                                                                 \
    {   float4 wv = *(const float4*)(vt + (T0));                               \
        int4   jv = *(const int4*)(ct + (T0));                                 \
        GQ(jv.x, wv.x); GQ(jv.y, wv.y); GQ(jv.z, wv.z); GQ(jv.w, wv.w); }

// ---------------- K1: agg[:,0:144] = support @ [y_basis | hx]  (bf16 out) ---
// chunks 0..8 compute 16 cols each; chunks 9..11 zero-fill pad cols 144..191.
__global__ __launch_bounds__(512, 4) void k_spmm1(
        const float* __restrict__ x, const float* __restrict__ hx,
        const float* __restrict__ vals, const int* __restrict__ cols,
        const int* __restrict__ nnz, u16* __restrict__ agg)
{
    __shared__ float s_hx[1024*16];        // 64 KB
    const int chunk = blockIdx.x;          // 0..11
    const int b     = blockIdx.y;
    const int tid   = threadIdx.x;
    float4* s4 = (float4*)s_hx;

    if (chunk >= 9){                       // zero-fill pad columns 144..191
        int cb = 144 + (chunk - 9) * 16;
        uint4 z = {0,0,0,0};
        for (int p = tid; p < 2048; p += 512){
            int node = p >> 1, half = p & 1;
            size_t m = (size_t)(b<<10) + node;
            *(uint4*)&agg[m*KP + cb + half*8] = z;
        }
        return;
    }

    const int cb = chunk * 16;
    for (int q = tid; q < 4096; q += 512){
        int row = q >> 2, qi = q & 3;
        int xscol = cb + qi*4;
        float4 v;
        if (xscol < 16)
            v = *(const float4*)&x[((size_t)((b<<10)+row))*16 + xscol];
        else
            v = *(const float4*)&hx[((size_t)((b<<10)+row))*128 + (xscol-16)];
        s4[row*4 + (qi ^ (row & 3))] = v;
    }
    __syncthreads();

    for (int p = tid; p < 4096; p += 512){
        int node = p >> 2, cq = p & 3;
        int c = nnz[node];
        const float* vt = vals + node*CAP;
        const int*   ct = cols + node*CAP;
        float4 acc = make_float4(0.f,0.f,0.f,0.f);
        GB(0) GB(4) GB(8) GB(12)                      // branch-free (zero-padded)
        for (int t0 = 16; t0 < c; t0 += 4) GB(t0)     // rare tail
        size_t m = (size_t)(b<<10) + node;
        ushort4 pv; pv.x = f2bf(acc.x); pv.y = f2bf(acc.y);
        pv.z = f2bf(acc.z); pv.w = f2bf(acc.w);
        *(ushort4*)&agg[m*KP + cb + cq*4] = pv;
    }
}

// ---------------- K3: agg[:,16:144] = support @ (r * hx)  (bf16 out) --------
__global__ __launch_bounds__(512, 4) void k_spmm2(
        const u16* __restrict__ value, const float* __restrict__ hx,
        const float* __restrict__ vals, const int* __restrict__ cols,
        const int* __restrict__ nnz, u16* __restrict__ agg)
{
    __shared__ float s_hx[1024*16];        // 64 KB
    const int chunk = blockIdx.x;          // 0..7 over hx cols
    const int b     = blockIdx.y;
    const int tid   = threadIdx.x;
    const int cb    = chunk * 16;
    float4* s4 = (float4*)s_hx;

    for (int q = tid; q < 4096; q += 512){
        int row = q >> 2, qi = q & 3;
        int hxcol = cb + qi*4;
        size_t nb = (size_t)((b<<10)+row);
        float4 h = *(const float4*)&hx[nb*128 + hxcol];
        ushort4 rv = *(const ushort4*)&value[nb*256 + hxcol];  // r = cols 0..127
        float4 v = make_float4(bf2f(rv.x)*h.x, bf2f(rv.y)*h.y,
                               bf2f(rv.z)*h.z, bf2f(rv.w)*h.w);
        s4[row*4 + (qi ^ (row & 3))] = v;
    }
    __syncthreads();

    for (int p = tid; p < 4096; p += 512){
        int node = p >> 2, cq = p & 3;
        int c = nnz[node];
        const float* vt = vals + node*CAP;
        const int*   ct = cols + node*CAP;
        float4 acc = make_float4(0.f,0.f,0.f,0.f);
        GB(0) GB(4) GB(8) GB(12)
        for (int t0 = 16; t0 < c; t0 += 4) GB(t0)
        size_t m = (size_t)(b<<10) + node;
        ushort4 pv; pv.x = f2bf(acc.x); pv.y = f2bf(acc.y);
        pv.z = f2bf(acc.z); pv.w = f2bf(acc.w);
        *(ushort4*)&agg[m*KP + D_ + cb + cq*4] = pv;
    }
}

// ============== MFMA GEMM core (bf16 inputs, f32 accum) ====================
// 128x128 tile, 4 waves (2x2), each wave 4x4 fragments of 16x16x32.
// LDS: A[128][72] + W[128][72] bf16 (stride 72 -> 2-way/free bank pattern).
// A-frag lane map: row=l&15, k=(l>>4)*8+j ; C/D: col=l&15, row=(l>>4)*4+reg.

#define GEMM_STAGE(DST, SRC, BASE)                                             \
    _Pragma("unroll")                                                          \
    for (int i = 0; i < 4; ++i){                                               \
        int q = tid + i*256;                                                   \
        int r_ = q >> 3, sl = q & 7;                                           \
        uint4 v = *(const uint4*)((SRC) + (size_t)((BASE)+r_)*KP + kb + sl*8); \
        *(uint4*)((DST) + r_*72 + sl*8) = v;                                   \
    }

#define GEMM_CORE                                                              \
    for (int kb = 0; kb < KP; kb += 64){                                       \
        __syncthreads();                                                       \
        GEMM_STAGE(a_s, agg, rb)                                               \
        GEMM_STAGE(w_s, wt, cb)                                                \
        __syncthreads();                                                       \
        _Pragma("unroll")                                                      \
        for (int ks = 0; ks < 2; ++ks){                                        \
            bf16x8 af[4], bfv[4];                                              \
            _Pragma("unroll")                                                  \
            for (int f = 0; f < 4; ++f){                                       \
                af[f]  = *(const bf16x8*)(a_s + (wr + f*16 + lrow)*72 + ks*32 + lk); \
                bfv[f] = *(const bf16x8*)(w_s + (wc + f*16 + lrow)*72 + ks*32 + lk); \
            }                                                                  \
            _Pragma("unroll")                                                  \
            for (int fr = 0; fr < 4; ++fr)                                     \
                _Pragma("unroll")                                              \
                for (int fc = 0; fc < 4; ++fc)                                 \
                    acc[fr][fc] = __builtin_amdgcn_mfma_f32_16x16x32_bf16(     \
                        af[fr], bfv[fc], acc[fr][fc], 0, 0, 0);                \
        }                                                                      \
    }

// ---------------- K2: value = sigmoid(agg @ kernel_r) -> bf16 ---------------
__global__ __launch_bounds__(256) void k_gemm1(const u16* __restrict__ agg,
        const u16* __restrict__ wt, u16* __restrict__ value)
{
    __shared__ u16 a_s[128*72];
    __shared__ u16 w_s[128*72];
    const int rb = blockIdx.x * 128, cb = blockIdx.y * 128;
    const int tid = threadIdx.x;
    const int wid = tid >> 6, lane = tid & 63;
    const int wr = (wid >> 1) * 64, wc = (wid & 1) * 64;
    const int lrow = lane & 15, lk = (lane >> 4) * 8;
    f32x4 acc[4][4] = {};
    GEMM_CORE
    const int rg = (lane >> 4) * 4;
    #pragma unroll
    for (int fr = 0; fr < 4; ++fr)
        #pragma unroll
        for (int fc = 0; fc < 4; ++fc)
            #pragma unroll
            for (int j = 0; j < 4; ++j){
                int row = rb + wr + fr*16 + rg + j;
                int col = cb + wc + fc*16 + lrow;
                value[(size_t)row*256 + col] = f2bf(sig_(acc[fr][fc][j]));
            }
}

// ---------------- K4: c=tanh(agg@kernel_c); new_state = hx*u + c*(1-u) -----
// value (bf16 r|u) lives IN the ns output slot; block owns rows rb..rb+127
// entirely (grid 1024x1): read u -> barrier -> store ns.
__global__ __launch_bounds__(256) void k_gemm2(const u16* __restrict__ agg,
        const u16* __restrict__ wt, const float* __restrict__ hx,
        const u16* value, float* ns_out)
{
    __shared__ u16 a_s[128*72];
    __shared__ u16 w_s[128*72];
    const int rb = blockIdx.x * 128, cb = 0;
    const int tid = threadIdx.x;
    const int wid = tid >> 6, lane = tid & 63;
    const int wr = (wid >> 1) * 64, wc = (wid & 1) * 64;
    const int lrow = lane & 15, lk = (lane >> 4) * 8;
    f32x4 acc[4][4] = {};
    GEMM_CORE
    const int rg = (lane >> 4) * 4;
    float ov[4][4][4];
    #pragma unroll
    for (int fr = 0; fr < 4; ++fr)
        #pragma unroll
        for (int fc = 0; fc < 4; ++fc)
            #pragma unroll
            for (int j = 0; j < 4; ++j){
                int row = rb + wr + fr*16 + rg + j;
                int col = wc + fc*16 + lrow;
                float u = bf2f(value[(size_t)row*256 + 128 + col]);
                float h = hx[(size_t)row*128 + col];
                float c = tanhf(acc[fr][fc][j]);
                ov[fr][fc][j] = h*u + c*(1.0f - u);
            }
    __syncthreads();   // all u-loads complete before anyone overwrites the slot
    #pragma unroll
    for (int fr = 0; fr < 4; ++fr)
        #pragma unroll
        for (int fc = 0; fc < 4; ++fc)
            #pragma unroll
            for (int j = 0; j < 4; ++j){
                int row = rb + wr + fr*16 + rg + j;
                int col = wc + fc*16 + lrow;
                ns_out[(size_t)row*128 + col] = ov[fr][fc][j];
            }
}

// ------- K5: o = [new_state | y_basis] @ w_out + b_out + new_delta; + nd ----
__global__ __launch_bounds__(256) void k_out(const float* __restrict__ ns,
        const float* __restrict__ x, const float* __restrict__ delta,
        const float* __restrict__ wo, const float* __restrict__ bo,
        const float* __restrict__ wb, const float* __restrict__ bb,
        const float* __restrict__ lam,
        float* __restrict__ o, float* __restrict__ nd_out)
{
    __shared__ float ns_s[64][132];
    __shared__ float yb_s[64][20];
    __shared__ float yr_s[64][20];
    __shared__ float w_s[144][16];
    __shared__ float wb_s[16][16];
    __shared__ float bo_s[16], bb_s[16];
    int rowbase = blockIdx.x * 64;
    int tid = threadIdx.x;
    const float* yr = x + (size_t)M_ * D_;      // x[1] = y_res
    #pragma unroll
    for (int jj = 0; jj < 8; ++jj){
        int q = tid + 256*jj;           // 2048 float4 = 64 rows x 128
        int row = q >> 5, c4 = (q & 31) * 4;
        *(float4*)&ns_s[row][c4] = *(const float4*)&ns[(size_t)(rowbase + row)*U_ + c4];
    }
    {
        int row = tid >> 2, c4 = (tid & 3) * 4;   // 256 float4 = 64 rows x 16
        *(float4*)&yb_s[row][c4] = *(const float4*)&x[(size_t)(rowbase + row)*D_ + c4];
        *(float4*)&yr_s[row][c4] = *(const float4*)&yr[(size_t)(rowbase + row)*D_ + c4];
    }
    #pragma unroll
    for (int jj = 0; jj < 3; ++jj){
        int q = tid + 256*jj;
        if (q < 576){ int k = q >> 2, d4 = (q & 3) * 4;
            *(float4*)&w_s[k][d4] = *(const float4*)&wo[k*D_ + d4]; }
    }
    wb_s[tid >> 4][tid & 15] = wb[tid];          // 256 = 16x16
    if (tid < 16){ bo_s[tid] = bo[tid]; bb_s[tid] = bb[tid]; }
    __syncthreads();
    int row = tid >> 2, d0 = (tid & 3) * 4;
    float4 acc = make_float4(0.f,0.f,0.f,0.f);
    for (int k = 0; k < U_; ++k){
        float cs = ns_s[row][k];
        float4 w = *(const float4*)&w_s[k][d0];
        acc.x = fmaf(cs, w.x, acc.x); acc.y = fmaf(cs, w.y, acc.y);
        acc.z = fmaf(cs, w.z, acc.z); acc.w = fmaf(cs, w.w, acc.w);
    }
    #pragma unroll
    for (int k = 0; k < D_; ++k){
        float cs = yb_s[row][k];
        float4 w = *(const float4*)&w_s[U_ + k][d0];
        acc.x = fmaf(cs, w.x, acc.x); acc.y = fmaf(cs, w.y, acc.y);
        acc.z = fmaf(cs, w.z, acc.z); acc.w = fmaf(cs, w.w, acc.w);
    }
    float4 dacc = make_float4(bb_s[d0], bb_s[d0+1], bb_s[d0+2], bb_s[d0+3]);
    #pragma unroll
    for (int k = 0; k < D_; ++k){
        float yv = yr_s[row][k];
        float4 w = *(const float4*)&wb_s[k][d0];
        dacc.x = fmaf(yv, w.x, dacc.x); dacc.y = fmaf(yv, w.y, dacc.y);
        dacc.z = fmaf(yv, w.z, dacc.z); dacc.w = fmaf(yv, w.w, dacc.w);
    }
    size_t off = (size_t)(rowbase + row)*D_ + d0;
    float4 dl = *(const float4*)&delta[off];
    float lm = lam[0];
    float nd4[4];
    float yv4[4] = {yr_s[row][d0], yr_s[row][d0+1], yr_s[row][d0+2], yr_s[row][d0+3]};
    float dv4[4] = {fmaxf(dacc.x,0.f), fmaxf(dacc.y,0.f), fmaxf(dacc.z,0.f), fmaxf(dacc.w,0.f)};
    float dl4[4] = {dl.x, dl.y, dl.z, dl.w};
    #pragma unroll
    for (int j = 0; j < 4; ++j){
        float pt = sig_(yv4[j] + 0.5f * sqrtf(fabsf(dl4[j] + 1e-9f)));
        nd4[j] = lm * (2.0f * pt - 1.0f) * dv4[j];
    }
    float4 bov = *(const float4*)&bo_s[d0];
    float4 ov = make_float4(acc.x + bov.x + nd4[0], acc.y + bov.y + nd4[1],
                            acc.z + bov.z + nd4[2], acc.w + bov.w + nd4[3]);
    *(float4*)&nd_out[off] = make_float4(nd4[0], nd4[1], nd4[2], nd4[3]);
    *(float4*)&o[off] = ov;
}

extern "C" void kernel_launch(void* const* d_in, const int* in_sizes, int n_in,
                              void* d_out, int out_size, void* d_ws, size_t ws_size,
                              hipStream_t stream)
{
    const float* x        = (const float*)d_in[0];
    const float* hx       = (const float*)d_in[1];
    const float* delta    = (const float*)d_in[2];
    const float* support  = (const float*)d_in[3];
    const float* kernel_r = (const float*)d_in[4];
    const float* kernel_c = (const float*)d_in[5];
    const float* w_out    = (const float*)d_in[6];
    const float* b_out    = (const float*)d_in[7];
    const float* w_basis  = (const float*)d_in[8];
    const float* b_basis  = (const float*)d_in[9];
    const float* lam      = (const float*)d_in[10];

    float* out = (float*)d_out;
    float* o   = out;                    // (B,N,D)   2,097,152
    float* ns  = out + 2097152;          // (B,N*U)  16,777,216
    float* nd  = out + 18874368;         // (B,N,D)   2,097,152
    u16*   value = (u16*)ns;             // bf16 [M][256] lives in ns slot

    char* ws = (char*)d_ws;
    float* ell_vals = (float*)ws;                       // 1024*48*4
    int*   ell_cols = (int*)(ws + 1024*CAP*4);          // 1024*48*4
    int*   ell_nnz  = (int*)(ws + 2*1024*CAP*4);        // 1024*4
    u16*   agg      = (u16*)(ws + (1 << 20));           // [M][192] bf16 = 50.3 MB
    u16*   wr_t     = (u16*)(ws + (1 << 20) + (size_t)M_*KP*2);          // 256*192
    u16*   wc_t     = wr_t + 256*KP;                                     // 128*192

    k_ell  <<<256, 256, 0, stream>>>(support, ell_vals, ell_cols, ell_nnz);
    k_prep <<<(256*KP + 128*KP)/256, 256, 0, stream>>>(kernel_r, kernel_c, wr_t, wc_t);
    k_spmm1<<<dim3(12,128), 512, 0, stream>>>(x, hx, ell_vals, ell_cols, ell_nnz, agg);
    k_gemm1<<<dim3(M_/128, 2), 256, 0, stream>>>(agg, wr_t, value);
    k_spmm2<<<dim3(8,128), 512, 0, stream>>>(value, hx, ell_vals, ell_cols, ell_nnz, agg);
    k_gemm2<<<M_/128, 256, 0, stream>>>(agg, wc_t, hx, value, ns);
    k_out  <<<M_/64, 256, 0, stream>>>(ns, x, delta, w_out, b_out,
                                       w_basis, b_basis, lam, o, nd);
}